// Round 1
// baseline (79.406 us; speedup 1.0000x reference)
//
#include <hip/hip_runtime.h>

#define D 32
#define L 32768           // 32*32*32
#define NC 96
#define LD 33             // padded LDS leading dim

// Output layout: out[b][s][c][l], s in 0..11, l in 0..L-1
// s = (q>>1)*4 + (q&1) for base scans q=0..5; flip scan = s+2.
// q0: l=(i,j,k)  q1: l=(i,k,j)  q2: l=(j,k,i)  q3: l=(j,i,k)  q4: l=(k,i,j)  q5: l=(k,j,i)
// input addr within slice = i*1024 + j*32 + k

__global__ __launch_bounds__(256) void cross_scan3d(const float* __restrict__ in,
                                                    float* __restrict__ out) {
    __shared__ float lds[D][LD];

    const int blk   = blockIdx.x;     // 0 .. B*C*6-1
    const int chunk = blockIdx.y;     // 0..3
    const int q  = blk % 6;
    const int bc = blk / 6;           // b*96 + c
    const int b  = bc / NC;
    const int c  = bc % NC;
    const int tid = threadIdx.x;

    const int s_base = (q >> 1) * 4 + (q & 1);

    const float4* in4 = (const float4*)(in + (size_t)bc * L);
    float4* o_base = (float4*)(out + ((size_t)(b * 12 + s_base)     * NC + c) * L);
    float4* o_flip = (float4*)(out + ((size_t)(b * 12 + s_base + 2) * NC + c) * L);

    if (q == 0) {
        // identity copy + reverse
        const int t0 = chunk * 2048;
        for (int t = t0 + tid; t < t0 + 2048; t += 256) {
            float4 v = in4[t];
            o_base[t] = v;
            float4 r = {v.w, v.z, v.y, v.x};
            o_flip[8191 - t] = r;
        }
    } else if (q == 3) {
        // l = j*1024 + i*32 + k : row remap (out row j*32+i <- in row i*32+j), k contiguous
        const int t0 = chunk * 2048;
        for (int t = t0 + tid; t < t0 + 2048; t += 256) {
            int c4  = t & 7;          // float4 within row
            int row = t >> 3;         // output row = j*32 + i
            int j = row >> 5, i = row & 31;
            float4 v = in4[(((i << 5) | j) << 3) + c4];
            o_base[t] = v;
            float4 r = {v.w, v.z, v.y, v.x};
            o_flip[8191 - t] = r;
        }
    } else {
        // Tiled transpose over (k, cc) planes, third dim w fixed per plane.
        //   input addr = w*Sw_in + cc*Sc_in + k
        //   output l   = w*Sw_out + k*Sk_out + cc
        const int Sw_in  = (q == 1 || q == 4) ? 1024 : 32;
        const int Sc_in  = 1056 - Sw_in;            // the other of {1024, 32}
        const int Sw_out = (q <= 2) ? 1024 : 32;    // q1,q2 -> 1024 ; q4,q5 -> 32
        const int Sk_out = 1056 - Sw_out;

        const float* src = in + (size_t)bc * L;

        const int cc_ld = tid >> 3, k4 = tid & 7;   // load indices
        const int k_st  = tid >> 3, c4 = tid & 7;   // store indices

        for (int w = chunk * 8; w < chunk * 8 + 8; ++w) {
            // load 32x32 plane, contiguous over k
            float4 v = ((const float4*)(src + w * Sw_in + cc_ld * Sc_in))[k4];
            lds[cc_ld][k4 * 4 + 0] = v.x;
            lds[cc_ld][k4 * 4 + 1] = v.y;
            lds[cc_ld][k4 * 4 + 2] = v.z;
            lds[cc_ld][k4 * 4 + 3] = v.w;
            __syncthreads();

            // store transposed, contiguous over cc
            int base_l = w * Sw_out + k_st * Sk_out;
            float4 o;
            o.x = lds[c4 * 4 + 0][k_st];
            o.y = lds[c4 * 4 + 1][k_st];
            o.z = lds[c4 * 4 + 2][k_st];
            o.w = lds[c4 * 4 + 3][k_st];
            o_base[(base_l >> 2) + c4] = o;
            float4 r = {o.w, o.z, o.y, o.x};
            o_flip[8191 - (base_l >> 2) - c4] = r;
            __syncthreads();
        }
    }
}

extern "C" void kernel_launch(void* const* d_in, const int* in_sizes, int n_in,
                              void* d_out, int out_size, void* d_ws, size_t ws_size,
                              hipStream_t stream) {
    const float* in = (const float*)d_in[0];
    float* out = (float*)d_out;
    const int bc_count = in_sizes[0] / L;   // B*C = 192
    dim3 grid(bc_count * 6, 4);
    cross_scan3d<<<grid, 256, 0, stream>>>(in, out);
}